// Round 2
// baseline (461.879 us; speedup 1.0000x reference)
//
#include <hip/hip_runtime.h>
#include <hip/hip_bf16.h>
#include <math.h>

// Top-p + exponential-minimum sampling, 5-kernel pipeline.
// Identities:
//   - sort by prob desc == sort by logit desc
//   - kept set == { l >= lambda* } where descending cumulative exp-mass
//     crosses TOP_P * total_mass (fp64 accumulation of f32 exp masses)
//   - argmin -log(xi)/p == argmin [ log(-log(xi)) - l ]  (monotone transform)
// K0: fill out with NEG_FILL, key[v]=log(-log(xi[v])), zero/init ws
// K1: per-(row,slice) LDS histogram of exp(l) over 4096 logit bins -> global merge
// K2: per-row descending scan -> boundary bin, cumAbove, target (fp64)
// K3: per-(row,slice) argmin over bins>B via packed u64 atomicMin; gather bin-B
// K4: per-row sort boundary list, fp64 crossing -> kept count, final winner,
//     store POS_FILL at [row, winner]

constexpr int   NBINS    = 4096;
constexpr int   CAP      = 1024;   // boundary-bin list capacity (~200 expected)
constexpr int   SLICES   = 8;
constexpr float BIN_MIN  = -8.0f;
constexpr float BIN_SCALE= 256.0f;
constexpr float NEG_FILL = -100000.0f;
constexpr float POS_FILL =  100000.0f;
constexpr float TOPP     = 0.9f;

struct Ws {
    float*  hist;      // [B][NBINS]
    float*  key;       // [V]  = log(-log(xi))
    double* cumAbove;  // [B]
    double* target;    // [B]
    unsigned long long* winner; // [B] packed (sortable_key<<32)|idx
    int*    binB;      // [B]
    int*    bcount;    // [B]
    float*  bl_l;      // [B][CAP]
    float*  bl_k;      // [B][CAP]  (key - l, the full score key)
    int*    bl_i;      // [B][CAP]
};

__device__ __forceinline__ unsigned sortable(float f) {
    unsigned u = __float_as_uint(f);
    return (u & 0x80000000u) ? ~u : (u | 0x80000000u);
}

// ---------------- K0: init ----------------
__global__ __launch_bounds__(256)
void k0_init(float* __restrict__ out, const float4* __restrict__ xi4,
             Ws ws, int B, int V)
{
    const long stride = (long)gridDim.x * blockDim.x;
    const long t = (long)blockIdx.x * blockDim.x + threadIdx.x;

    // fill output with NEG_FILL
    const long total4 = (long)B * V / 4;
    float4* out4 = reinterpret_cast<float4*>(out);
    const float4 nf = make_float4(NEG_FILL, NEG_FILL, NEG_FILL, NEG_FILL);
    for (long i = t; i < total4; i += stride) out4[i] = nf;

    // zero histograms
    const long hist4 = (long)B * NBINS / 4;
    float4* h4 = reinterpret_cast<float4*>(ws.hist);
    const float4 z = make_float4(0.f, 0.f, 0.f, 0.f);
    for (long i = t; i < hist4; i += stride) h4[i] = z;

    // key[v] = log(-log(xi[v]))  (once; shared by all rows)
    const long V4 = V / 4;
    float4* key4 = reinterpret_cast<float4*>(ws.key);
    for (long i = t; i < V4; i += stride) {
        float4 x = xi4[i];
        float4 k;
        k.x = logf(-logf(x.x));
        k.y = logf(-logf(x.y));
        k.z = logf(-logf(x.z));
        k.w = logf(-logf(x.w));
        key4[i] = k;
    }

    // misc per-row init
    for (long i = t; i < B; i += stride) {
        ws.winner[i] = ~0ull;
        ws.bcount[i] = 0;
    }
}

// ---------------- K1: histogram ----------------
__global__ __launch_bounds__(256)
void k1_hist(const float* __restrict__ logits, Ws ws, int V)
{
    const int row = blockIdx.x / SLICES;
    const int sl  = blockIdx.x % SLICES;
    const int n4  = V / 4 / SLICES;
    const float4* p4 = reinterpret_cast<const float4*>(logits + (size_t)row * V) + sl * n4;

    __shared__ float lh[NBINS];
    for (int i = threadIdx.x; i < NBINS; i += 256) lh[i] = 0.f;
    __syncthreads();

    for (int j = threadIdx.x; j < n4; j += 256) {
        float4 L = p4[j];
        float lv[4] = {L.x, L.y, L.z, L.w};
        #pragma unroll
        for (int c = 0; c < 4; ++c) {
            float l = lv[c];
            int b = (int)floorf((l - BIN_MIN) * BIN_SCALE);
            b = min(max(b, 0), NBINS - 1);
            atomicAdd(&lh[b], expf(l));
        }
    }
    __syncthreads();

    float* gh = ws.hist + (size_t)row * NBINS;
    for (int b = threadIdx.x; b < NBINS; b += 256) {
        float h = lh[b];
        if (h != 0.f) atomicAdd(&gh[b], h);
    }
}

// ---------------- K2: per-row descending scan ----------------
__global__ __launch_bounds__(64)
void k2_scan(Ws ws)
{
    const int row = blockIdx.x;
    const float* gh = ws.hist + (size_t)row * NBINS;
    const int lane = threadIdx.x;
    const int hi = NBINS - 1 - (lane << 6);

    double seg = 0.0;
    for (int k = 0; k < 64; ++k) seg += (double)gh[hi - k];

    double v = seg;
    for (int off = 1; off < 64; off <<= 1) {
        double u = __shfl_up(v, off);
        if (lane >= off) v += u;
    }
    double excl   = v - seg;
    double total  = __shfl(v, 63);
    double target = (double)TOPP * total;

    int    candBin = -1;
    double candS   = 0.0;
    double cum     = excl;
    for (int k = 0; k < 64; ++k) {
        int b = hi - k;
        double h = (double)gh[b];
        if (candBin < 0 && cum + h >= target) { candBin = b; candS = cum; }
        cum += h;
    }
    for (int off = 32; off >= 1; off >>= 1) {
        int    ob = __shfl_xor(candBin, off);
        double os = __shfl_xor(candS, off);
        if (ob > candBin) { candBin = ob; candS = os; }
    }
    if (lane == 0) {
        ws.binB[row]     = candBin;
        ws.cumAbove[row] = candS;
        ws.target[row]   = target;
    }
}

// ---------------- K3: select / argmin ----------------
__global__ __launch_bounds__(256)
void k3_select(const float* __restrict__ logits, Ws ws, int V)
{
    const int row = blockIdx.x / SLICES;
    const int sl  = blockIdx.x % SLICES;
    const int n4  = V / 4 / SLICES;
    const int base4 = sl * n4;
    const float4* p4 = reinterpret_cast<const float4*>(logits + (size_t)row * V) + base4;
    const float4* k4 = reinterpret_cast<const float4*>(ws.key) + base4;
    const int binB = ws.binB[row];

    unsigned long long best = ~0ull;
    for (int j = threadIdx.x; j < n4; j += 256) {
        float4 L = p4[j];
        float4 K = k4[j];
        float lv[4] = {L.x, L.y, L.z, L.w};
        float kv[4] = {K.x, K.y, K.z, K.w};
        #pragma unroll
        for (int c = 0; c < 4; ++c) {
            float l = lv[c];
            int b = (int)floorf((l - BIN_MIN) * BIN_SCALE);
            b = min(max(b, 0), NBINS - 1);
            if (b > binB) {
                float kk = kv[c] - l;
                unsigned long long pack =
                    ((unsigned long long)sortable(kk) << 32) |
                    (unsigned)((base4 + j) * 4 + c);
                best = pack < best ? pack : best;
            } else if (b == binB) {
                int p = atomicAdd(&ws.bcount[row], 1);
                if (p < CAP) {
                    ws.bl_l[(size_t)row * CAP + p] = l;
                    ws.bl_k[(size_t)row * CAP + p] = kv[c] - l;
                    ws.bl_i[(size_t)row * CAP + p] = (base4 + j) * 4 + c;
                }
            }
        }
    }

    // block min-reduce of packed best
    for (int off = 32; off >= 1; off >>= 1) {
        unsigned long long o = __shfl_down(best, off);
        best = o < best ? o : best;
    }
    __shared__ unsigned long long wr[4];
    if ((threadIdx.x & 63) == 0) wr[threadIdx.x >> 6] = best;
    __syncthreads();
    if (threadIdx.x == 0) {
        unsigned long long b0 = wr[0];
        for (int w = 1; w < 4; ++w) b0 = wr[w] < b0 ? wr[w] : b0;
        atomicMin(&ws.winner[row], b0);
    }
}

// ---------------- K4: boundary resolve + final store ----------------
__global__ __launch_bounds__(256)
void k4_final(float* __restrict__ out, Ws ws, int V)
{
    const int row = blockIdx.x;
    __shared__ float s_l[CAP];
    __shared__ float s_k[CAP];
    __shared__ int   s_i[CAP];
    __shared__ int   sKept;
    __shared__ unsigned long long wr[4];

    int n = ws.bcount[row];
    if (n > CAP) n = CAP;
    int P = 1; while (P < n) P <<= 1;
    if (P < 2) P = 2;

    for (int i = threadIdx.x; i < P; i += 256) {
        if (i < n) {
            s_l[i] = ws.bl_l[(size_t)row * CAP + i];
            s_k[i] = ws.bl_k[(size_t)row * CAP + i];
            s_i[i] = ws.bl_i[(size_t)row * CAP + i];
        } else {
            s_l[i] = -INFINITY; s_k[i] = 0.f; s_i[i] = 0x7fffffff;
        }
    }

    // bitonic sort: l descending, idx ascending on ties (match stable argsort)
    for (int size = 2; size <= P; size <<= 1) {
        for (int stride = size >> 1; stride > 0; stride >>= 1) {
            __syncthreads();
            for (int i = threadIdx.x; i < P; i += 256) {
                int j = i ^ stride;
                if (j > i) {
                    float li = s_l[i], lj = s_l[j];
                    int   ii = s_i[i], ij = s_i[j];
                    bool iLessJ = (li < lj) || (li == lj && ii > ij); // i "after" j in desc order
                    bool up = ((i & size) == 0);
                    bool sw = up ? iLessJ : !iLessJ && !(li == lj && ii == ij);
                    if (up ? iLessJ : ((li > lj) || (li == lj && ii < ij))) {
                        s_l[i] = lj; s_l[j] = li;
                        float tk = s_k[i]; s_k[i] = s_k[j]; s_k[j] = tk;
                        s_i[i] = ij; s_i[j] = ii;
                    }
                    (void)sw;
                }
            }
        }
    }
    __syncthreads();

    // fp64 sequential crossing within the boundary bin
    if (threadIdx.x == 0) {
        double cum = ws.cumAbove[row];
        double target = ws.target[row];
        int kept = n;
        for (int k = 0; k < n; ++k) {
            cum += (double)expf(s_l[k]);
            if (cum >= target) { kept = k + 1; break; }
        }
        sKept = kept;
    }
    __syncthreads();

    // merge kept boundary tokens into the argmin
    const int keptN = sKept;
    unsigned long long lb = ~0ull;
    for (int k = threadIdx.x; k < keptN; k += 256) {
        unsigned long long pack =
            ((unsigned long long)sortable(s_k[k]) << 32) | (unsigned)s_i[k];
        lb = pack < lb ? pack : lb;
    }
    for (int off = 32; off >= 1; off >>= 1) {
        unsigned long long o = __shfl_down(lb, off);
        lb = o < lb ? o : lb;
    }
    if ((threadIdx.x & 63) == 0) wr[threadIdx.x >> 6] = lb;
    __syncthreads();
    if (threadIdx.x == 0) {
        unsigned long long b = wr[0];
        for (int w = 1; w < 4; ++w) b = wr[w] < b ? wr[w] : b;
        unsigned long long gw = ws.winner[row];
        b = gw < b ? gw : b;
        int win = (int)(b & 0xffffffffu);
        out[(size_t)row * V + win] = POS_FILL;
    }
}

extern "C" void kernel_launch(void* const* d_in, const int* in_sizes, int n_in,
                              void* d_out, int out_size, void* d_ws, size_t ws_size,
                              hipStream_t stream) {
    // d_in[0] = input_ids (int64, unused)
    // d_in[1] = logits f32 [B, V]
    // d_in[2] = xi     f32 [V]
    const float* logits = (const float*)d_in[1];
    const float* xi     = (const float*)d_in[2];
    float*       out    = (float*)d_out;
    const int V = in_sizes[2];
    const int B = in_sizes[1] / V;

    char* w = (char*)d_ws;
    size_t off = 0;
    Ws ws;
    ws.hist     = (float*)(w + off);  off += (size_t)B * NBINS * sizeof(float);
    ws.key      = (float*)(w + off);  off += (size_t)V * sizeof(float);
    off = (off + 255) & ~(size_t)255;
    ws.cumAbove = (double*)(w + off); off += (size_t)B * sizeof(double);
    ws.target   = (double*)(w + off); off += (size_t)B * sizeof(double);
    ws.winner   = (unsigned long long*)(w + off); off += (size_t)B * sizeof(unsigned long long);
    ws.binB     = (int*)(w + off);    off += (size_t)B * sizeof(int);
    ws.bcount   = (int*)(w + off);    off += (size_t)B * sizeof(int);
    off = (off + 255) & ~(size_t)255;
    ws.bl_l     = (float*)(w + off);  off += (size_t)B * CAP * sizeof(float);
    ws.bl_k     = (float*)(w + off);  off += (size_t)B * CAP * sizeof(float);
    ws.bl_i     = (int*)(w + off);    off += (size_t)B * CAP * sizeof(int);

    k0_init  <<<2048, 256, 0, stream>>>(out, (const float4*)xi, ws, B, V);
    k1_hist  <<<B * SLICES, 256, 0, stream>>>(logits, ws, V);
    k2_scan  <<<B, 64, 0, stream>>>(ws);
    k3_select<<<B * SLICES, 256, 0, stream>>>(logits, ws, V);
    k4_final <<<B, 256, 0, stream>>>(out, ws, V);
}

// Round 5
// 420.252 us; speedup vs baseline: 1.0991x; 1.0991x over previous
//
#include <hip/hip_runtime.h>
#include <hip/hip_bf16.h>
#include <math.h>

// Top-p + exponential-minimum sampling, 3-kernel pipeline, ZERO global atomics.
//   - sort by prob desc == sort by logit desc
//   - kept set == { l >= lambda* } where descending cumulative exp-mass
//     crosses TOP_P * total_mass (fp64 accumulation of f32 exp masses)
//   - argmin -log(xi)/p == argmin [ log(-log(xi)) - l ]  (monotone transform)
// KA: fill out with NEG_FILL; key[v] = log(-log(xi[v]))
// KB: per-row block: LDS histogram of exp(l) over 4096 logit bins (LDS atomics
//     only) + fused wave-0 descending scan -> binB, cumAbove, target
// KC: per-row block: batched re-read (L3-hot), register argmin over bins>binB,
//     LDS gather of boundary bin, bitonic sort, fp64 crossing, final store.

constexpr int   NBINS     = 4096;
constexpr int   CAP       = 1024;   // boundary-bin capacity (~191 expected, sigma~14)
constexpr float BIN_MIN   = -8.0f;
constexpr float BIN_SCALE = 256.0f;
constexpr float NEG_FILL  = -100000.0f;
constexpr float POS_FILL  =  100000.0f;
constexpr float TOPP      = 0.9f;

struct Ws {
    float*  key;       // [V] = log(-log(xi))
    int*    binB;      // [B]
    double* cumAbove;  // [B]
    double* target;    // [B]
};

__device__ __forceinline__ unsigned sortable(float f) {
    unsigned u = __float_as_uint(f);
    return (u & 0x80000000u) ? ~u : (u | 0x80000000u);
}
__device__ __forceinline__ int binOf(float l) {
    int b = (int)floorf((l - BIN_MIN) * BIN_SCALE);
    return min(max(b, 0), NBINS - 1);
}

// ---------------- KA: init ----------------
__global__ __launch_bounds__(256)
void ka_init(float* __restrict__ out, const float4* __restrict__ xi4,
             float* __restrict__ key, long total4, int V4)
{
    const long stride = (long)gridDim.x * 256;
    const long t = (long)blockIdx.x * 256 + threadIdx.x;

    float4* out4 = reinterpret_cast<float4*>(out);
    const float4 nf = make_float4(NEG_FILL, NEG_FILL, NEG_FILL, NEG_FILL);
    for (long i = t; i < total4; i += stride) out4[i] = nf;

    float4* key4 = reinterpret_cast<float4*>(key);
    for (long i = t; i < V4; i += stride) {
        float4 x = xi4[i];
        float4 k;
        k.x = logf(-logf(x.x));
        k.y = logf(-logf(x.y));
        k.z = logf(-logf(x.z));
        k.w = logf(-logf(x.w));
        key4[i] = k;
    }
}

// ---------------- KB: per-row histogram + fused scan ----------------
__global__ __launch_bounds__(1024)
void kb_hist_scan(const float* __restrict__ logits, Ws ws, int V)
{
    const int row = blockIdx.x;
    const int tid = threadIdx.x;
    const int n4  = V >> 2;
    const float4* p4 = reinterpret_cast<const float4*>(logits + (size_t)row * V);

    __shared__ float lh[NBINS];
    for (int i = tid; i < NBINS; i += 1024) lh[i] = 0.f;
    __syncthreads();

    // 4-deep batched float4 loads for memory-level parallelism
    for (int base = 0; base < n4; base += 4096) {
        float4 r[4];
        int    j[4];
        #pragma unroll
        for (int u = 0; u < 4; ++u) {
            j[u] = base + u * 1024 + tid;
            if (j[u] < n4) r[u] = p4[j[u]];
        }
        #pragma unroll
        for (int u = 0; u < 4; ++u) {
            if (j[u] < n4) {
                float lv[4] = {r[u].x, r[u].y, r[u].z, r[u].w};
                #pragma unroll
                for (int c = 0; c < 4; ++c)
                    atomicAdd(&lh[binOf(lv[c])], expf(lv[c]));
            }
        }
    }
    __syncthreads();

    // wave-0 descending scan over 4096 bins
    if (tid < 64) {
        const int lane = tid;
        const int hi = NBINS - 1 - (lane << 6);
        double seg = 0.0;
        for (int k = 0; k < 64; ++k) seg += (double)lh[hi - k];

        double v = seg;
        for (int off = 1; off < 64; off <<= 1) {
            double u = __shfl_up(v, off);
            if (lane >= off) v += u;
        }
        double excl   = v - seg;
        double total  = __shfl(v, 63);
        double target = (double)TOPP * total;

        int    candBin = -1;
        double candS   = 0.0;
        double cum     = excl;
        for (int k = 0; k < 64; ++k) {
            int b = hi - k;
            double h = (double)lh[b];
            if (candBin < 0 && cum + h >= target) { candBin = b; candS = cum; }
            cum += h;
        }
        for (int off = 32; off >= 1; off >>= 1) {
            int    ob = __shfl_xor(candBin, off);
            double os = __shfl_xor(candS, off);
            if (ob > candBin) { candBin = ob; candS = os; }
        }
        if (lane == 0) {
            ws.binB[row]     = candBin;
            ws.cumAbove[row] = candS;
            ws.target[row]   = target;
        }
    }
}

// ---------------- KC: select + boundary resolve + final store ----------------
__global__ __launch_bounds__(1024)
void kc_select(const float* __restrict__ logits, float* __restrict__ out,
               Ws ws, int V)
{
    const int row = blockIdx.x;
    const int tid = threadIdx.x;
    const int n4  = V >> 2;
    const float4* p4 = reinterpret_cast<const float4*>(logits + (size_t)row * V);
    const float4* k4 = reinterpret_cast<const float4*>(ws.key);
    const int binB = ws.binB[row];

    __shared__ float s_l[CAP];
    __shared__ float s_k[CAP];
    __shared__ float s_e[CAP];
    __shared__ int   s_i[CAP];
    __shared__ int   s_cnt;
    __shared__ int   sKept;
    __shared__ unsigned long long wr[16];

    if (tid == 0) s_cnt = 0;
    __syncthreads();

    unsigned long long best = ~0ull;

    for (int base = 0; base < n4; base += 4096) {
        float4 r[4], x[4];
        int    j[4];
        #pragma unroll
        for (int u = 0; u < 4; ++u) {
            j[u] = base + u * 1024 + tid;
            if (j[u] < n4) { r[u] = p4[j[u]]; x[u] = k4[j[u]]; }
        }
        #pragma unroll
        for (int u = 0; u < 4; ++u) {
            if (j[u] < n4) {
                float lv[4] = {r[u].x, r[u].y, r[u].z, r[u].w};
                float kv[4] = {x[u].x, x[u].y, x[u].z, x[u].w};
                #pragma unroll
                for (int c = 0; c < 4; ++c) {
                    float l = lv[c];
                    int b = binOf(l);
                    if (b > binB) {
                        unsigned long long pack =
                            ((unsigned long long)sortable(kv[c] - l) << 32) |
                            (unsigned)(j[u] * 4 + c);
                        best = pack < best ? pack : best;
                    } else if (b == binB) {
                        int p = atomicAdd(&s_cnt, 1);
                        if (p < CAP) {
                            s_l[p] = l;
                            s_k[p] = kv[c] - l;
                            s_i[p] = j[u] * 4 + c;
                        }
                    }
                }
            }
        }
    }
    __syncthreads();

    // bitonic sort boundary list: l desc, idx asc on ties (stable-argsort match)
    int n = s_cnt; if (n > CAP) n = CAP;
    int P = 1; while (P < n) P <<= 1;
    if (P < 2) P = 2;
    for (int i = tid; i < P; i += 1024) {
        if (i >= n) { s_l[i] = -INFINITY; s_k[i] = 0.f; s_i[i] = 0x7fffffff; }
    }
    for (int size = 2; size <= P; size <<= 1) {
        for (int stride = size >> 1; stride > 0; stride >>= 1) {
            __syncthreads();
            if (tid < P) {
                int i = tid, jj = tid ^ stride;
                if (jj > i) {
                    float li = s_l[i], lj = s_l[jj];
                    int   ii = s_i[i], ij = s_i[jj];
                    bool up = ((i & size) == 0);
                    bool iBeforeJ = (li > lj) || (li == lj && ii < ij); // descending
                    bool sw = up ? !iBeforeJ && !(li == lj && ii == ij)
                                 : iBeforeJ;
                    if (sw) {
                        s_l[i] = lj; s_l[jj] = li;
                        float tk = s_k[i]; s_k[i] = s_k[jj]; s_k[jj] = tk;
                        s_i[i] = ij; s_i[jj] = ii;
                    }
                }
            }
        }
    }
    __syncthreads();

    // exp in parallel, then fp64 serial crossing by thread 0
    for (int i = tid; i < n; i += 1024) s_e[i] = expf(s_l[i]);
    __syncthreads();
    if (tid == 0) {
        double cum    = ws.cumAbove[row];
        double target = ws.target[row];
        int kept = n;
        for (int k = 0; k < n; ++k) {
            cum += (double)s_e[k];
            if (cum >= target) { kept = k + 1; break; }
        }
        sKept = kept;
    }
    __syncthreads();

    // merge kept boundary tokens into per-thread best, then one block reduce
    const int keptN = sKept;
    for (int k = tid; k < keptN; k += 1024) {
        unsigned long long pack =
            ((unsigned long long)sortable(s_k[k]) << 32) | (unsigned)s_i[k];
        best = pack < best ? pack : best;
    }
    for (int off = 32; off >= 1; off >>= 1) {
        unsigned long long o = __shfl_down(best, off);
        best = o < best ? o : best;
    }
    if ((tid & 63) == 0) wr[tid >> 6] = best;
    __syncthreads();
    if (tid == 0) {
        unsigned long long b = wr[0];
        for (int w = 1; w < 16; ++w) b = wr[w] < b ? wr[w] : b;
        out[(size_t)row * V + (unsigned)(b & 0xffffffffu)] = POS_FILL;
    }
}

extern "C" void kernel_launch(void* const* d_in, const int* in_sizes, int n_in,
                              void* d_out, int out_size, void* d_ws, size_t ws_size,
                              hipStream_t stream) {
    // d_in[0] = input_ids (int64, unused)
    // d_in[1] = logits f32 [B, V]
    // d_in[2] = xi     f32 [V]
    const float* logits = (const float*)d_in[1];
    const float* xi     = (const float*)d_in[2];
    float*       out    = (float*)d_out;
    const int V = in_sizes[2];
    const int B = in_sizes[1] / V;

    char* w = (char*)d_ws;
    size_t off = 0;
    Ws ws;
    ws.key      = (float*)(w + off);  off += (size_t)V * sizeof(float);
    off = (off + 255) & ~(size_t)255;
    ws.binB     = (int*)(w + off);    off += (size_t)B * sizeof(int);
    off = (off + 255) & ~(size_t)255;
    ws.cumAbove = (double*)(w + off); off += (size_t)B * sizeof(double);
    ws.target   = (double*)(w + off); off += (size_t)B * sizeof(double);

    const long total4 = (long)B * V / 4;
    ka_init     <<<2048, 256, 0, stream>>>(out, (const float4*)xi, ws.key, total4, V / 4);
    kb_hist_scan<<<B, 1024, 0, stream>>>(logits, ws, V);
    kc_select   <<<B, 1024, 0, stream>>>(logits, out, ws, V);
}

// Round 6
// 300.147 us; speedup vs baseline: 1.5388x; 1.4002x over previous
//
#include <hip/hip_runtime.h>
#include <hip/hip_bf16.h>
#include <math.h>

// Top-p + exponential-minimum sampling, 4-kernel pipeline.
// Identities:
//   - sort by prob desc == sort by logit desc
//   - kept set == { l >= lambda* } where descending cumulative exp-mass
//     crosses TOP_P * total_mass
//   - argmin -log(xi)/p == argmin [ log(-log(xi)) - l ]  (monotone transform)
// Masses are FIXED-POINT u32: m = round(exp(l)*4096)  -> native ds_add_u32
// (f32 LDS atomicAdd is a ~200-cycle CAS loop on gfx950 — measured r2/r5).
// K0: key[v] = log(-log(xi[v]))               (tiny)
// KB: per-row block: u32 LDS histogram over 4096 logit bins + fused wave-0
//     descending scan -> binB, cumAbove, target    (HBM read-bound)
// KC: per-row block: re-read logits (L3-hot; nothing evicted in between),
//     register argmin over bins>binB, LDS gather of bin B, bitonic sort,
//     fixed-point crossing, winner -> ws             (L3 read-bound)
// KD: fill out with NEG_FILL, POS_FILL at winner     (HBM write-bound)

constexpr int   NBINS     = 4096;
constexpr int   CAP       = 1024;   // boundary-bin capacity (~200 expected)
constexpr float BIN_MIN   = -8.0f;
constexpr float BIN_SCALE = 256.0f;
constexpr float MASS_SCALE= 4096.0f;
constexpr float NEG_FILL  = -100000.0f;
constexpr float POS_FILL  =  100000.0f;
constexpr float TOPP      = 0.9f;
constexpr int   BPR_FILL  = 32;     // fill blocks per row

struct Ws {
    float*  key;       // [V] = log(-log(xi))
    int*    binB;      // [B]
    double* cumAbove;  // [B]  (fixed-point units)
    double* target;    // [B]  (fixed-point units)
    unsigned long long* winner; // [B] packed (sortable(score)<<32)|idx
};

__device__ __forceinline__ unsigned sortable(float f) {
    unsigned u = __float_as_uint(f);
    return (u & 0x80000000u) ? ~u : (u | 0x80000000u);
}
__device__ __forceinline__ int binOf(float l) {
    int b = (int)floorf((l - BIN_MIN) * BIN_SCALE);
    return min(max(b, 0), NBINS - 1);
}
// identical expression in KB and KC -> bit-consistent masses
__device__ __forceinline__ unsigned massOf(float l) {
    return __float2uint_rn(__expf(l) * MASS_SCALE);
}

// ---------------- K0: key precompute ----------------
__global__ __launch_bounds__(256)
void k0_key(const float4* __restrict__ xi4, float* __restrict__ key, int V4)
{
    const int stride = gridDim.x * 256;
    float4* key4 = reinterpret_cast<float4*>(key);
    for (int i = blockIdx.x * 256 + threadIdx.x; i < V4; i += stride) {
        float4 x = xi4[i];
        float4 k;
        k.x = __logf(-__logf(x.x));
        k.y = __logf(-__logf(x.y));
        k.z = __logf(-__logf(x.z));
        k.w = __logf(-__logf(x.w));
        key4[i] = k;
    }
}

// ---------------- KB: per-row u32 histogram + fused scan ----------------
__global__ __launch_bounds__(1024)
void kb_hist_scan(const float* __restrict__ logits, Ws ws, int V)
{
    const int row = blockIdx.x;
    const int tid = threadIdx.x;
    const int n4  = V >> 2;
    const float4* p4 = reinterpret_cast<const float4*>(logits + (size_t)row * V);

    __shared__ unsigned lh[NBINS];
    for (int i = tid; i < NBINS; i += 1024) lh[i] = 0u;
    __syncthreads();

    for (int base = 0; base < n4; base += 4096) {
        float4 r[4];
        int    j[4];
        #pragma unroll
        for (int u = 0; u < 4; ++u) {
            j[u] = base + u * 1024 + tid;
            if (j[u] < n4) r[u] = p4[j[u]];
        }
        #pragma unroll
        for (int u = 0; u < 4; ++u) {
            if (j[u] < n4) {
                float lv[4] = {r[u].x, r[u].y, r[u].z, r[u].w};
                #pragma unroll
                for (int c = 0; c < 4; ++c)
                    atomicAdd(&lh[binOf(lv[c])], massOf(lv[c]));  // ds_add_u32
            }
        }
    }
    __syncthreads();

    // wave-0 descending scan over 4096 bins (fp64, exact on u32 inputs)
    if (tid < 64) {
        const int lane = tid;
        const int hi = NBINS - 1 - (lane << 6);
        double seg = 0.0;
        for (int k = 0; k < 64; ++k) seg += (double)lh[hi - k];

        double v = seg;
        for (int off = 1; off < 64; off <<= 1) {
            double u = __shfl_up(v, off);
            if (lane >= off) v += u;
        }
        double excl   = v - seg;
        double total  = __shfl(v, 63);
        double target = (double)TOPP * total;

        int    candBin = -1;
        double candS   = 0.0;
        double cum     = excl;
        for (int k = 0; k < 64; ++k) {
            int b = hi - k;
            double h = (double)lh[b];
            if (candBin < 0 && cum + h >= target) { candBin = b; candS = cum; }
            cum += h;
        }
        for (int off = 32; off >= 1; off >>= 1) {
            int    ob = __shfl_xor(candBin, off);
            double os = __shfl_xor(candS, off);
            if (ob > candBin) { candBin = ob; candS = os; }
        }
        if (lane == 0) {
            ws.binB[row]     = candBin;
            ws.cumAbove[row] = candS;
            ws.target[row]   = target;
        }
    }
}

// ---------------- KC: select + boundary resolve -> winner ----------------
__global__ __launch_bounds__(1024)
void kc_select(const float* __restrict__ logits, Ws ws, int V)
{
    const int row = blockIdx.x;
    const int tid = threadIdx.x;
    const int n4  = V >> 2;
    const float4* p4 = reinterpret_cast<const float4*>(logits + (size_t)row * V);
    const float4* k4 = reinterpret_cast<const float4*>(ws.key);
    const int binB = ws.binB[row];

    __shared__ float s_l[CAP];
    __shared__ float s_k[CAP];
    __shared__ unsigned s_m[CAP];
    __shared__ int   s_i[CAP];
    __shared__ int   s_cnt;
    __shared__ int   sKept;
    __shared__ unsigned long long wr[16];

    if (tid == 0) s_cnt = 0;
    __syncthreads();

    unsigned long long best = ~0ull;

    for (int base = 0; base < n4; base += 4096) {
        float4 r[4], x[4];
        int    j[4];
        #pragma unroll
        for (int u = 0; u < 4; ++u) {
            j[u] = base + u * 1024 + tid;
            if (j[u] < n4) { r[u] = p4[j[u]]; x[u] = k4[j[u]]; }
        }
        #pragma unroll
        for (int u = 0; u < 4; ++u) {
            if (j[u] < n4) {
                float lv[4] = {r[u].x, r[u].y, r[u].z, r[u].w};
                float kv[4] = {x[u].x, x[u].y, x[u].z, x[u].w};
                #pragma unroll
                for (int c = 0; c < 4; ++c) {
                    float l = lv[c];
                    int b = binOf(l);
                    if (b > binB) {
                        unsigned long long pack =
                            ((unsigned long long)sortable(kv[c] - l) << 32) |
                            (unsigned)(j[u] * 4 + c);
                        best = pack < best ? pack : best;
                    } else if (b == binB) {
                        int p = atomicAdd(&s_cnt, 1);   // ds_add_u32, rare
                        if (p < CAP) {
                            s_l[p] = l;
                            s_k[p] = kv[c] - l;
                            s_i[p] = j[u] * 4 + c;
                        }
                    }
                }
            }
        }
    }
    __syncthreads();

    // bitonic sort boundary list: l desc, idx asc on ties
    int n = s_cnt; if (n > CAP) n = CAP;
    int P = 1; while (P < n) P <<= 1;
    if (P < 2) P = 2;
    for (int i = tid; i < P; i += 1024) {
        if (i >= n) { s_l[i] = -INFINITY; s_k[i] = 0.f; s_i[i] = 0x7fffffff; }
    }
    for (int size = 2; size <= P; size <<= 1) {
        for (int stride = size >> 1; stride > 0; stride >>= 1) {
            __syncthreads();
            if (tid < P) {
                int i = tid, jj = tid ^ stride;
                if (jj > i) {
                    float li = s_l[i], lj = s_l[jj];
                    int   ii = s_i[i], ij = s_i[jj];
                    bool up = ((i & size) == 0);
                    bool iBeforeJ = (li > lj) || (li == lj && ii < ij); // descending
                    bool sw = up ? (!iBeforeJ && !(li == lj && ii == ij))
                                 : iBeforeJ;
                    if (sw) {
                        s_l[i] = lj; s_l[jj] = li;
                        float tk = s_k[i]; s_k[i] = s_k[jj]; s_k[jj] = tk;
                        s_i[i] = ij; s_i[jj] = ii;
                    }
                }
            }
        }
    }
    __syncthreads();

    // masses in parallel (same expression as KB -> bit-consistent)
    for (int i = tid; i < n; i += 1024) s_m[i] = massOf(s_l[i]);
    __syncthreads();
    if (tid == 0) {
        double cum    = ws.cumAbove[row];
        double target = ws.target[row];
        int kept = n;
        for (int k = 0; k < n; ++k) {
            cum += (double)s_m[k];
            if (cum >= target) { kept = k + 1; break; }
        }
        sKept = kept;
    }
    __syncthreads();

    const int keptN = sKept;
    for (int k = tid; k < keptN; k += 1024) {
        unsigned long long pack =
            ((unsigned long long)sortable(s_k[k]) << 32) | (unsigned)s_i[k];
        best = pack < best ? pack : best;
    }
    for (int off = 32; off >= 1; off >>= 1) {
        unsigned long long o = __shfl_down(best, off);
        best = o < best ? o : best;
    }
    if ((tid & 63) == 0) wr[tid >> 6] = best;
    __syncthreads();
    if (tid == 0) {
        unsigned long long b = wr[0];
        for (int w = 1; w < 16; ++w) b = wr[w] < b ? wr[w] : b;
        ws.winner[row] = b;
    }
}

// ---------------- KD: fill output ----------------
__global__ __launch_bounds__(256)
void kd_fill(float* __restrict__ out,
             const unsigned long long* __restrict__ winner, int V)
{
    const int row = blockIdx.x / BPR_FILL;
    const int seg = blockIdx.x % BPR_FILL;
    const int n4  = V >> 2;
    const int per = n4 / BPR_FILL;
    float4* o4 = reinterpret_cast<float4*>(out + (size_t)row * V) + seg * per;

    const unsigned win = (unsigned)(winner[row] & 0xffffffffu);
    const int local = (int)(win >> 2) - seg * per;   // float4 slot within segment

    const float4 nf = make_float4(NEG_FILL, NEG_FILL, NEG_FILL, NEG_FILL);
    for (int j = threadIdx.x; j < per; j += 256) {
        float4 v = nf;
        if (j == local) {
            float ov[4] = {v.x, v.y, v.z, v.w};
            ov[win & 3] = POS_FILL;
            v = make_float4(ov[0], ov[1], ov[2], ov[3]);
        }
        o4[j] = v;
    }
}

extern "C" void kernel_launch(void* const* d_in, const int* in_sizes, int n_in,
                              void* d_out, int out_size, void* d_ws, size_t ws_size,
                              hipStream_t stream) {
    // d_in[0] = input_ids (int64, unused)
    // d_in[1] = logits f32 [B, V]
    // d_in[2] = xi     f32 [V]
    const float* logits = (const float*)d_in[1];
    const float* xi     = (const float*)d_in[2];
    float*       out    = (float*)d_out;
    const int V = in_sizes[2];
    const int B = in_sizes[1] / V;

    char* w = (char*)d_ws;
    size_t off = 0;
    Ws ws;
    ws.key      = (float*)(w + off);  off += (size_t)V * sizeof(float);
    off = (off + 255) & ~(size_t)255;
    ws.binB     = (int*)(w + off);    off += (size_t)B * sizeof(int);
    off = (off + 255) & ~(size_t)255;
    ws.cumAbove = (double*)(w + off); off += (size_t)B * sizeof(double);
    ws.target   = (double*)(w + off); off += (size_t)B * sizeof(double);
    ws.winner   = (unsigned long long*)(w + off); off += (size_t)B * sizeof(unsigned long long);

    k0_key      <<<128, 256, 0, stream>>>((const float4*)xi, ws.key, V / 4);
    kb_hist_scan<<<B, 1024, 0, stream>>>(logits, ws, V);
    kc_select   <<<B, 1024, 0, stream>>>(logits, ws, V);
    kd_fill     <<<B * BPR_FILL, 256, 0, stream>>>(out, ws.winner, V);
}

// Round 7
// 291.150 us; speedup vs baseline: 1.5864x; 1.0309x over previous
//
#include <hip/hip_runtime.h>
#include <hip/hip_bf16.h>
#include <math.h>

// Top-p + exponential-minimum sampling.
//   - sort by prob desc == sort by logit desc
//   - kept set == { (l,idx) >= (l_cut,idx_cut) } via descending exp-mass crossing
//   - argmin -log(xi)/p == argmin [ key[v] - l ],  key = log(-log(xi))
// Structure:
//   K0: key[v]; per-1024-token chunk, compact candidates {key < -3} into fixed
//       sentinel-padded slots (no global atomics). Only these can win: a token
//       with key >= -3 needs l - key >= d* ~ 11  ->  l >= 8 (impossible).
//       Proof is re-checked per row at runtime; fallback = exact full sweep.
//   KB (one block per row): subsample -> boundary-bin window estimate;
//       full sweep: count-histogram (u32 ds_add) + lmax + stash window tokens;
//       fp64 descending scan with count[b]*exp(center_b) -> bin B, cumAbove,
//       target; filter stash to bin B, bitonic sort, fp64-exp crossing ->
//       (l_cut, idx_cut); candidate gather argmin over kept; safety check;
//       (fallback sweeps if window missed / overflow / proof fails).
//   KD: fill out with NEG_FILL, POS_FILL at winner.

constexpr int   NBINS     = 4096;
constexpr float BIN_MIN   = -8.0f;
constexpr float BIN_SCALE = 256.0f;
constexpr float BIN_OFF   = 2048.0f;       // -BIN_MIN*BIN_SCALE
constexpr float BIN_W     = 1.0f / 256.0f;
constexpr int   STASH_CAP = 4096;
constexpr int   BINB_CAP  = 512;
constexpr int   WIN       = 6;             // stash window half-width (bins)
constexpr int   MAXC      = 96;            // candidate slots per 1024-token chunk
constexpr float CAND_THR  = -3.0f;
constexpr float NEG_FILL  = -100000.0f;
constexpr float POS_FILL  =  100000.0f;
constexpr float TOPP      = 0.9f;
constexpr int   BPR_FILL  = 32;

struct Ws {
    float*    key;      // [V]
    unsigned* candIdx;  // [nchunk*MAXC]
    float*    candKey;  // [nchunk*MAXC]  (INF sentinel padding)
    int*      candCnt;  // [nchunk]
    unsigned long long* winner; // [B]
};

__device__ __forceinline__ unsigned sortable(float f) {
    unsigned u = __float_as_uint(f);
    return (u & 0x80000000u) ? ~u : (u | 0x80000000u);
}
__device__ __forceinline__ int binOf(float l) {
    int b = (int)fmaf(l, BIN_SCALE, BIN_OFF);   // trunc==floor for arg>=0; clamp fixes rest
    return min(max(b, 0), NBINS - 1);
}

// ---------------- K0: keys + candidate compaction ----------------
__global__ __launch_bounds__(256)
void k0_keys(const float4* __restrict__ xi4, float* __restrict__ key,
             unsigned* __restrict__ candIdx, float* __restrict__ candKey,
             int* __restrict__ candCnt, int V4)
{
    __shared__ int cnt;
    __shared__ unsigned sIdx[MAXC];
    __shared__ float    sKey[MAXC];
    if (threadIdx.x == 0) cnt = 0;
    __syncthreads();

    const int f = blockIdx.x * 256 + threadIdx.x;
    if (f < V4) {
        float4 x = xi4[f];
        float kv[4];
        kv[0] = __logf(-__logf(x.x));
        kv[1] = __logf(-__logf(x.y));
        kv[2] = __logf(-__logf(x.z));
        kv[3] = __logf(-__logf(x.w));
        reinterpret_cast<float4*>(key)[f] = make_float4(kv[0], kv[1], kv[2], kv[3]);
        #pragma unroll
        for (int c = 0; c < 4; ++c) {
            if (kv[c] < CAND_THR) {
                int p = atomicAdd(&cnt, 1);
                if (p < MAXC) { sIdx[p] = (unsigned)(f * 4 + c); sKey[p] = kv[c]; }
            }
        }
    }
    __syncthreads();
    const int base = blockIdx.x * MAXC;
    const int n = min(cnt, MAXC);
    for (int i = threadIdx.x; i < MAXC; i += 256) {
        candIdx[base + i] = (i < n) ? sIdx[i] : 0u;
        candKey[base + i] = (i < n) ? sKey[i] : INFINITY;
    }
    if (threadIdx.x == 0) candCnt[blockIdx.x] = cnt;
}

// ---------------- descending scan helper (wave 0, lanes 0..63) -----------
__device__ __forceinline__ void scan_bins(const unsigned* lh, int lane,
                                          int& candBin, double& candS, double& target)
{
    const int hi = NBINS - 1 - (lane << 6);
    double seg = 0.0;
    for (int k = 0; k < 64; ++k) {
        int b = hi - k;
        seg += (double)lh[b] * (double)__expf(fmaf((float)b + 0.5f, BIN_W, BIN_MIN));
    }
    double v = seg;
    for (int off = 1; off < 64; off <<= 1) {
        double u = __shfl_up(v, off);
        if (lane >= off) v += u;
    }
    double excl = v - seg;
    double total = __shfl(v, 63);
    target = TOPP * total;

    candBin = -1; candS = 0.0;
    double cum = excl;
    for (int k = 0; k < 64; ++k) {
        int b = hi - k;
        double h = (double)lh[b] * (double)__expf(fmaf((float)b + 0.5f, BIN_W, BIN_MIN));
        if (candBin < 0 && cum + h >= target) { candBin = b; candS = cum; }
        cum += h;
    }
    for (int off = 32; off >= 1; off >>= 1) {
        int    ob = __shfl_xor(candBin, off);
        double os = __shfl_xor(candS, off);
        if (ob > candBin) { candBin = ob; candS = os; }
    }
}

// ---------------- KB: per-row everything ----------------
__global__ __launch_bounds__(1024)
void kb_row(const float* __restrict__ logits, const float* __restrict__ key,
            const unsigned* __restrict__ candIdx, const float* __restrict__ candKey,
            const int* __restrict__ candCnt, unsigned long long* __restrict__ winner,
            int V, int nchunk, int nslots)
{
    const int row = blockIdx.x;
    const int tid = threadIdx.x;
    const int n4  = V >> 2;
    const float* rowp = logits + (size_t)row * V;
    const float4* p4 = reinterpret_cast<const float4*>(rowp);

    __shared__ unsigned lh[NBINS];
    __shared__ float  s_sl[STASH_CAP];
    __shared__ int    s_si[STASH_CAP];
    __shared__ float  s_bl[BINB_CAP];
    __shared__ int    s_bi[BINB_CAP];
    __shared__ double s_be[BINB_CAP];
    __shared__ unsigned long long wrd[16];
    __shared__ float  wrf[16];
    __shared__ int   sStashCnt, sB2, sBtil, sB, sM, sNeedFull, sCandOver;
    __shared__ float sLmax, sLcut;
    __shared__ int   sIcut;
    __shared__ double sCumAbove, sTarget;
    __shared__ unsigned long long sBest;

    // init + candidate-overflow check
    for (int i = tid; i < NBINS; i += 1024) lh[i] = 0u;
    if (tid == 0) { sStashCnt = 0; sB2 = 0; sCandOver = 0; sNeedFull = 0; }
    __syncthreads();
    if (tid < nchunk && candCnt[tid] > MAXC) atomicOr(&sCandOver, 1);

    // ---- subsample (32K elems) for window estimate ----
    for (int k = 0; k < 8; ++k) {
        int j = tid + k * 4000;
        float4 L = p4[j];
        atomicAdd(&lh[binOf(L.x)], 1u);
        atomicAdd(&lh[binOf(L.y)], 1u);
        atomicAdd(&lh[binOf(L.z)], 1u);
        atomicAdd(&lh[binOf(L.w)], 1u);
    }
    __syncthreads();
    if (tid < 64) {
        int b; double cs, tg;
        scan_bins(lh, tid, b, cs, tg);
        if (tid == 0) sBtil = b;
    }
    __syncthreads();
    const int wlo = max(0, sBtil - WIN);
    const int whi = min(NBINS - 1, sBtil + WIN);

    // re-zero hist
    for (int i = tid; i < NBINS; i += 1024) lh[i] = 0u;
    __syncthreads();

    // ---- full sweep: count hist + lmax + window stash ----
    float lmax = -INFINITY;
    for (int j = tid; j < n4; j += 1024) {
        float4 L = p4[j];
        float lv[4] = {L.x, L.y, L.z, L.w};
        #pragma unroll
        for (int c = 0; c < 4; ++c) {
            float l = lv[c];
            int b = binOf(l);
            atomicAdd(&lh[b], 1u);
            lmax = fmaxf(lmax, l);
            if ((unsigned)(b - wlo) <= (unsigned)(whi - wlo)) {
                int p = atomicAdd(&sStashCnt, 1);
                if (p < STASH_CAP) { s_sl[p] = l; s_si[p] = j * 4 + c; }
            }
        }
    }
    // lmax block reduce
    for (int off = 32; off >= 1; off >>= 1)
        lmax = fmaxf(lmax, __shfl_down(lmax, off));
    if ((tid & 63) == 0) wrf[tid >> 6] = lmax;
    __syncthreads();
    if (tid == 0) {
        float m = wrf[0];
        for (int w = 1; w < 16; ++w) m = fmaxf(m, wrf[w]);
        sLmax = m;
    }
    __syncthreads();

    // ---- main scan ----
    if (tid < 64) {
        int b; double cs, tg;
        scan_bins(lh, tid, b, cs, tg);
        if (tid == 0) { sB = b; sCumAbove = cs; sTarget = tg; }
    }
    __syncthreads();
    const int B = sB;

    // ---- build bin-B list (from stash, or regather if window missed) ----
    const bool stashOK = (B >= wlo) && (B <= whi) && (sStashCnt <= STASH_CAP);
    if (stashOK) {
        const int n = sStashCnt;
        for (int i = tid; i < n; i += 1024) {
            float l = s_sl[i];
            if (binOf(l) == B) {
                int q = atomicAdd(&sB2, 1);
                if (q < BINB_CAP) { s_bl[q] = l; s_bi[q] = s_si[i]; }
            }
        }
    } else {
        for (int j = tid; j < n4; j += 1024) {
            float4 L = p4[j];
            float lv[4] = {L.x, L.y, L.z, L.w};
            #pragma unroll
            for (int c = 0; c < 4; ++c) {
                if (binOf(lv[c]) == B) {
                    int q = atomicAdd(&sB2, 1);
                    if (q < BINB_CAP) { s_bl[q] = lv[c]; s_bi[q] = j * 4 + c; }
                }
            }
        }
    }
    __syncthreads();
    int nB = min(sB2, BINB_CAP);
    if (sB2 > BINB_CAP && tid == 0) sNeedFull = 1;   // cannot resolve -> exact path

    // ---- bitonic sort bin-B desc by (l, idx asc) ----
    int P = 1; while (P < nB) P <<= 1;
    if (P < 2) P = 2;
    for (int i = tid; i < P; i += 1024)
        if (i >= nB) { s_bl[i] = -INFINITY; s_bi[i] = 0x7fffffff; }
    for (int size = 2; size <= P; size <<= 1) {
        for (int stride = size >> 1; stride > 0; stride >>= 1) {
            __syncthreads();
            if (tid < P) {
                int i = tid, jj = tid ^ stride;
                if (jj > i) {
                    float li = s_bl[i], lj = s_bl[jj];
                    int   ii = s_bi[i], ij = s_bi[jj];
                    bool up = ((i & size) == 0);
                    bool iBeforeJ = (li > lj) || (li == lj && ii < ij);
                    bool sw = up ? (!iBeforeJ && !(li == lj && ii == ij)) : iBeforeJ;
                    if (sw) {
                        s_bl[i] = lj; s_bl[jj] = li;
                        s_bi[i] = ij; s_bi[jj] = ii;
                    }
                }
            }
        }
    }
    __syncthreads();

    // ---- fp64 crossing -> (l_cut, idx_cut) ----
    for (int i = tid; i < nB; i += 1024) s_be[i] = exp((double)s_bl[i]);
    __syncthreads();
    if (tid == 0) {
        double cum = sCumAbove, target = sTarget;
        int m = nB;
        for (int k = 0; k < nB; ++k) {
            cum += s_be[k];
            if (cum >= target) { m = k + 1; break; }
        }
        m = max(m, 1);
        sM = m;
        sLcut = s_bl[m - 1];
        sIcut = s_bi[m - 1];
    }
    __syncthreads();
    const float lcut = sLcut;
    const int   icut = sIcut;

    // ---- candidate argmin over kept ----
    unsigned long long best = ~0ull;
    for (int s = tid; s < nslots; s += 1024) {
        unsigned idx = candIdx[s];
        float ck = candKey[s];
        float l = rowp[idx];
        bool kept = (l > lcut) || (l == lcut && (int)idx <= icut);
        if (kept) {
            unsigned long long pack =
                ((unsigned long long)sortable(ck - l) << 32) | idx;
            best = pack < best ? pack : best;
        }
    }
    for (int off = 32; off >= 1; off >>= 1) {
        unsigned long long o = __shfl_down(best, off);
        best = o < best ? o : best;
    }
    if ((tid & 63) == 0) wrd[tid >> 6] = best;
    __syncthreads();
    if (tid == 0) {
        unsigned long long b = wrd[0];
        for (int w = 1; w < 16; ++w) b = wrd[w] < b ? wrd[w] : b;
        sBest = b;
        // safety proof: every non-candidate has key >= CAND_THR, so its score
        // >= CAND_THR - lmax. Require bestScore < CAND_THR - lmax strictly.
        unsigned bound = sortable(CAND_THR - sLmax);
        if (!((unsigned)(b >> 32) < bound) || sCandOver) sNeedFull = 1;
    }
    __syncthreads();

    // ---- exact fallback (never taken in practice) ----
    if (sNeedFull) {
        for (int j = tid; j < V; j += 1024) {
            float l = rowp[j];
            bool kept = (l > lcut) || (l == lcut && j <= icut);
            if (kept) {
                unsigned long long pack =
                    ((unsigned long long)sortable(key[j] - l) << 32) | (unsigned)j;
                best = pack < best ? pack : best;
            }
        }
        for (int off = 32; off >= 1; off >>= 1) {
            unsigned long long o = __shfl_down(best, off);
            best = o < best ? o : best;
        }
        if ((tid & 63) == 0) wrd[tid >> 6] = best;
        __syncthreads();
        if (tid == 0) {
            unsigned long long b = sBest;
            for (int w = 0; w < 16; ++w) b = wrd[w] < b ? wrd[w] : b;
            sBest = b;
        }
        __syncthreads();
    }

    if (tid == 0) winner[row] = sBest;
}

// ---------------- KD: fill output ----------------
__global__ __launch_bounds__(256)
void kd_fill(float* __restrict__ out,
             const unsigned long long* __restrict__ winner, int V)
{
    const int row = blockIdx.x / BPR_FILL;
    const int seg = blockIdx.x % BPR_FILL;
    const int n4  = V >> 2;
    const int per = n4 / BPR_FILL;
    const int start = seg * per;
    const int end = (seg == BPR_FILL - 1) ? n4 : start + per;
    float4* o4 = reinterpret_cast<float4*>(out + (size_t)row * V);

    const unsigned win = (unsigned)(winner[row] & 0xffffffffu);
    const int winj = (int)(win >> 2);

    const float4 nf = make_float4(NEG_FILL, NEG_FILL, NEG_FILL, NEG_FILL);
    for (int j = start + threadIdx.x; j < end; j += 256) {
        float4 v = nf;
        if (j == winj) {
            float ov[4] = {v.x, v.y, v.z, v.w};
            ov[win & 3] = POS_FILL;
            v = make_float4(ov[0], ov[1], ov[2], ov[3]);
        }
        o4[j] = v;
    }
}

extern "C" void kernel_launch(void* const* d_in, const int* in_sizes, int n_in,
                              void* d_out, int out_size, void* d_ws, size_t ws_size,
                              hipStream_t stream) {
    // d_in[0] = input_ids (int64, unused)
    // d_in[1] = logits f32 [B, V]
    // d_in[2] = xi     f32 [V]
    const float* logits = (const float*)d_in[1];
    const float* xi     = (const float*)d_in[2];
    float*       out    = (float*)d_out;
    const int V = in_sizes[2];
    const int B = in_sizes[1] / V;
    const int V4 = V / 4;
    const int nchunk = (V + 1023) / 1024;
    const int nslots = nchunk * MAXC;

    char* w = (char*)d_ws;
    size_t off = 0;
    Ws ws;
    ws.key     = (float*)(w + off);    off += (size_t)V * sizeof(float);
    off = (off + 255) & ~(size_t)255;
    ws.candIdx = (unsigned*)(w + off); off += (size_t)nslots * sizeof(unsigned);
    ws.candKey = (float*)(w + off);    off += (size_t)nslots * sizeof(float);
    ws.candCnt = (int*)(w + off);      off += (size_t)nchunk * sizeof(int);
    off = (off + 255) & ~(size_t)255;
    ws.winner  = (unsigned long long*)(w + off); off += (size_t)B * sizeof(unsigned long long);

    k0_keys<<<(V4 + 255) / 256, 256, 0, stream>>>((const float4*)xi, ws.key,
                                                  ws.candIdx, ws.candKey, ws.candCnt, V4);
    kb_row <<<B, 1024, 0, stream>>>(logits, ws.key, ws.candIdx, ws.candKey,
                                    ws.candCnt, ws.winner, V, nchunk, nslots);
    kd_fill<<<B * BPR_FILL, 256, 0, stream>>>(out, ws.winner, V);
}